// Round 1
// baseline (421.262 us; speedup 1.0000x reference)
//
#include <hip/hip_runtime.h>
#include <cstdint>
#include <math.h>

#define B_ 8
#define L_ 2048
#define D_ 2048
#define R_ 256

typedef __bf16 bf16x8 __attribute__((ext_vector_type(8)));
typedef float f32x4 __attribute__((ext_vector_type(4)));

__device__ __forceinline__ unsigned short f2bf(float f) {
    uint32_t u = __builtin_bit_cast(uint32_t, f);
    u += 0x7FFFu + ((u >> 16) & 1u);
    return (unsigned short)(u >> 16);
}

#define GLDS16(gp, lp)                                                          \
    __builtin_amdgcn_global_load_lds(                                           \
        (const __attribute__((address_space(1))) void*)(gp),                    \
        (__attribute__((address_space(3))) void*)(lp), 16, 0, 0)

// ---------------------------------------------------------------------------
// Kernel 1: LayerNorm (fp32 -> bf16) + per-row mean of x_norm (feat)
// one block per (b,l) row; 256 threads, 8 elems/thread
// ---------------------------------------------------------------------------
__global__ __launch_bounds__(256) void ln_kernel(
    const float* __restrict__ x, const float* __restrict__ gamma,
    const float* __restrict__ beta, unsigned short* __restrict__ xn,
    float* __restrict__ feat)
{
    const int row  = blockIdx.x;
    const int t    = threadIdx.x;
    const int w    = t >> 6, lane = t & 63;
    const float4* x4 = (const float4*)(x + (size_t)row * D_);
    float4 a = x4[t];
    float4 b = x4[t + 256];
    float s  = a.x + a.y + a.z + a.w + b.x + b.y + b.z + b.w;
    float sq = a.x*a.x + a.y*a.y + a.z*a.z + a.w*a.w
             + b.x*b.x + b.y*b.y + b.z*b.z + b.w*b.w;
    __shared__ float red[12];
#pragma unroll
    for (int o = 32; o; o >>= 1) { s += __shfl_down(s, o); sq += __shfl_down(sq, o); }
    if (lane == 0) { red[w] = s; red[4 + w] = sq; }
    __syncthreads();
    float S    = red[0] + red[1] + red[2] + red[3];
    float SQ   = red[4] + red[5] + red[6] + red[7];
    float mean = S * (1.0f / D_);
    float var  = SQ * (1.0f / D_) - mean * mean;
    float rstd = rsqrtf(var + 1e-5f);

    const float4* g4 = (const float4*)gamma;
    const float4* b4 = (const float4*)beta;
    float4 g0 = g4[t], g1 = g4[t + 256];
    float4 e0 = b4[t], e1 = b4[t + 256];

    float n[8];
    n[0] = (a.x - mean) * rstd * g0.x + e0.x;
    n[1] = (a.y - mean) * rstd * g0.y + e0.y;
    n[2] = (a.z - mean) * rstd * g0.z + e0.z;
    n[3] = (a.w - mean) * rstd * g0.w + e0.w;
    n[4] = (b.x - mean) * rstd * g1.x + e1.x;
    n[5] = (b.y - mean) * rstd * g1.y + e1.y;
    n[6] = (b.z - mean) * rstd * g1.z + e1.z;
    n[7] = (b.w - mean) * rstd * g1.w + e1.w;

    ushort4 o0, o1;
    o0.x = f2bf(n[0]); o0.y = f2bf(n[1]); o0.z = f2bf(n[2]); o0.w = f2bf(n[3]);
    o1.x = f2bf(n[4]); o1.y = f2bf(n[5]); o1.z = f2bf(n[6]); o1.w = f2bf(n[7]);
    ((ushort4*)(xn + (size_t)row * D_))[t]       = o0;
    ((ushort4*)(xn + (size_t)row * D_))[t + 256] = o1;

    float fs = n[0]+n[1]+n[2]+n[3]+n[4]+n[5]+n[6]+n[7];
#pragma unroll
    for (int o = 32; o; o >>= 1) fs += __shfl_down(fs, o);
    if (lane == 0) red[8 + w] = fs;
    __syncthreads();
    if (t == 0) feat[row] = (red[8] + red[9] + red[10] + red[11]) * (1.0f / D_);
}

// ---------------------------------------------------------------------------
// Kernel 2: P (D x R fp32) -> PT (R x D bf16)
// ---------------------------------------------------------------------------
__global__ __launch_bounds__(256) void pt_kernel(
    const float* __restrict__ P, unsigned short* __restrict__ PT)
{
    int k = blockIdx.x;   // 0..2047 (D)
    int r = threadIdx.x;  // 0..255  (R)
    PT[(size_t)r * D_ + k] = f2bf(P[(size_t)k * R_ + r]);
}

// ---------------------------------------------------------------------------
// Kernel 3: W2T[s][q] = sum_r dlt_T[r][q] * toep[r - s + 127]   (dlt^T @ Tm)
// ---------------------------------------------------------------------------
__global__ __launch_bounds__(256) void w2_kernel(
    const float* __restrict__ dlt, const float* __restrict__ toep,
    float* __restrict__ W2T)
{
    int s = blockIdx.x, q = threadIdx.x;
    int r0 = s - 127; if (r0 < 0) r0 = 0;
    int r1 = s + 127; if (r1 > 255) r1 = 255;
    float acc = 0.f;
    for (int r = r0; r <= r1; r++)
        acc += dlt[(size_t)r * R_ + q] * toep[r - s + 127];
    W2T[(size_t)s * R_ + q] = acc;
}

// ---------------------------------------------------------------------------
// Kernel 4: WT[d][q] = sum_s W2T[s][q] * Wq[s][d]   -> bf16 (W_eff transposed)
// ---------------------------------------------------------------------------
__global__ __launch_bounds__(256) void wt_kernel(
    const float* __restrict__ W2T, const float* __restrict__ Wq,
    unsigned short* __restrict__ WT)
{
    int d = blockIdx.x, q = threadIdx.x;
    float acc = 0.f;
    for (int s = 0; s < R_; s++)
        acc += W2T[(size_t)s * R_ + q] * Wq[(size_t)s * D_ + d];
    WT[(size_t)d * R_ + q] = f2bf(acc);
}

// ---------------------------------------------------------------------------
// Kernel 5: per-feature scale: gs[l] = g(l)*scale[l], bgs[l] = bq[l]*gs[l]
// scale[l] = (det*sum_k cos(pi*(l+.5)*k/L) + sum_r phi_bias[l,r]
//             + featbar[l]*sum_r phi_w[r]) / R
// ---------------------------------------------------------------------------
__global__ __launch_bounds__(256) void scale_kernel(
    const float* __restrict__ phi_bias, const float* __restrict__ phi_w,
    const float* __restrict__ feat, const float* __restrict__ bq,
    const float* __restrict__ g_logit, const int* __restrict__ step,
    float* __restrict__ gs, float* __restrict__ bgs)
{
    int l = blockIdx.x, k = threadIdx.x;
    int w = k >> 6, lane = k & 63;
    double arg = 3.14159265358979323846 * ((double)l + 0.5) * (double)k / (double)L_;
    float cv = (float)cos(arg);
    float pb = phi_bias[(size_t)l * R_ + k];
    float pw = phi_w[k];
    __shared__ float red[12];
#pragma unroll
    for (int o = 32; o; o >>= 1) {
        cv += __shfl_down(cv, o);
        pb += __shfl_down(pb, o);
        pw += __shfl_down(pw, o);
    }
    if (lane == 0) { red[w] = cv; red[4 + w] = pb; red[8 + w] = pw; }
    __syncthreads();
    if (k == 0) {
        float cs  = red[0] + red[1] + red[2] + red[3];
        float pbs = red[4] + red[5] + red[6] + red[7];
        float pws = red[8] + red[9] + red[10] + red[11];
        float fb = 0.f;
        for (int b = 0; b < B_; b++) fb += feat[(size_t)b * L_ + l];
        fb *= (1.0f / B_);
        float det = fminf((float)step[0] / 2000.0f, 1.0f);
        float sc  = (det * cs + pbs + fb * pws) * (1.0f / R_);
        float gl  = g_logit[l >> 10];
        float gg  = 1.0f / (1.0f + expf(-gl));
        gs[l]  = gg * sc;
        bgs[l] = bq[l] * gg * sc;
    }
}

// ---------------------------------------------------------------------------
// GEMM1: u(bf16, 16384x256) = xn(16384x2048 bf16) @ P  (via PT, N x K)
// BM=64, BN=128, BK=32; 256 thr = 4 waves (2x2), wave tile 32x64 (2x4 frags)
// ---------------------------------------------------------------------------
__global__ __launch_bounds__(256, 2) void gemm1_kernel(
    const unsigned short* __restrict__ A,   // xn, lda=2048
    const unsigned short* __restrict__ BT,  // PT,  ldb=2048
    unsigned short* __restrict__ U)         // 16384x256
{
    __shared__ __align__(16) unsigned short sA[64 * 32];
    __shared__ __align__(16) unsigned short sB[128 * 32];
    const int tid  = threadIdx.x;
    const int m0   = blockIdx.x * 64;
    const int n0   = blockIdx.y * 128;
    const int w    = tid >> 6, lane = tid & 63;
    const int quad = lane >> 4, m16 = lane & 15;
    const int wm   = (w >> 1) * 32, wn = (w & 1) * 64;

    f32x4 acc[2][4] = {};

    for (int kc = 0; kc < 2048; kc += 32) {
        {   // A: 64 rows x 32 -> 256 lanes x 16B
            int r = tid >> 2, seg = tid & 3;
            GLDS16(A + (size_t)(m0 + r) * 2048 + kc + seg * 8, sA + tid * 8);
        }
#pragma unroll
        for (int i = 0; i < 2; i++) {   // B: 128 rows x 32 -> 512 x 16B
            int idx = i * 256 + tid;
            int r = idx >> 2, seg = idx & 3;
            GLDS16(BT + (size_t)(n0 + r) * 2048 + kc + seg * 8, sB + idx * 8);
        }
        __syncthreads();
        bf16x8 af[2], bf[4];
#pragma unroll
        for (int i = 0; i < 2; i++)
            af[i] = *(const bf16x8*)(sA + ((wm + i * 16 + m16) * 32 + quad * 8));
#pragma unroll
        for (int j = 0; j < 4; j++)
            bf[j] = *(const bf16x8*)(sB + ((wn + j * 16 + m16) * 32 + quad * 8));
#pragma unroll
        for (int i = 0; i < 2; i++)
#pragma unroll
            for (int j = 0; j < 4; j++)
                acc[i][j] = __builtin_amdgcn_mfma_f32_16x16x32_bf16(
                    af[i], bf[j], acc[i][j], 0, 0, 0);
        __syncthreads();
    }

#pragma unroll
    for (int i = 0; i < 2; i++)
#pragma unroll
        for (int j = 0; j < 4; j++) {
            int col = n0 + wn + j * 16 + m16;
#pragma unroll
            for (int r = 0; r < 4; r++) {
                int row = m0 + wm + i * 16 + quad * 4 + r;
                U[(size_t)row * 256 + col] = f2bf(acc[i][j][r]);
            }
        }
}

// ---------------------------------------------------------------------------
// GEMM2: out(16384x2048 f32) = u(16384x256) @ W_eff (via WT, N x K)
//        epilogue: *gs[col] + bgs[col]
// BM=128, BN=128, BK=32; wave tile 64x64 (4x4 frags)
// ---------------------------------------------------------------------------
__global__ __launch_bounds__(256, 2) void gemm2_kernel(
    const unsigned short* __restrict__ A,   // u,  lda=256
    const unsigned short* __restrict__ BT,  // WT, ldb=256
    const float* __restrict__ gs, const float* __restrict__ bgs,
    float* __restrict__ out)
{
    __shared__ __align__(16) unsigned short sA[128 * 32];
    __shared__ __align__(16) unsigned short sB[128 * 32];
    const int tid  = threadIdx.x;
    const int m0   = blockIdx.x * 128;
    const int n0   = blockIdx.y * 128;
    const int w    = tid >> 6, lane = tid & 63;
    const int quad = lane >> 4, m16 = lane & 15;
    const int wm   = (w >> 1) * 64, wn = (w & 1) * 64;

    f32x4 acc[4][4] = {};

    for (int kc = 0; kc < 256; kc += 32) {
#pragma unroll
        for (int i = 0; i < 2; i++) {
            int idx = i * 256 + tid;
            int r = idx >> 2, seg = idx & 3;
            GLDS16(A + (size_t)(m0 + r) * 256 + kc + seg * 8, sA + idx * 8);
            GLDS16(BT + (size_t)(n0 + r) * 256 + kc + seg * 8, sB + idx * 8);
        }
        __syncthreads();
        bf16x8 af[4], bf[4];
#pragma unroll
        for (int i = 0; i < 4; i++)
            af[i] = *(const bf16x8*)(sA + ((wm + i * 16 + m16) * 32 + quad * 8));
#pragma unroll
        for (int j = 0; j < 4; j++)
            bf[j] = *(const bf16x8*)(sB + ((wn + j * 16 + m16) * 32 + quad * 8));
#pragma unroll
        for (int i = 0; i < 4; i++)
#pragma unroll
            for (int j = 0; j < 4; j++)
                acc[i][j] = __builtin_amdgcn_mfma_f32_16x16x32_bf16(
                    af[i], bf[j], acc[i][j], 0, 0, 0);
        __syncthreads();
    }

#pragma unroll
    for (int j = 0; j < 4; j++) {
        int col = n0 + wn + j * 16 + m16;
        float gv = gs[col], bv = bgs[col];
#pragma unroll
        for (int i = 0; i < 4; i++)
#pragma unroll
            for (int r = 0; r < 4; r++) {
                int row = m0 + wm + i * 16 + quad * 4 + r;
                out[(size_t)row * 2048 + col] = acc[i][j][r] * gv + bv;
            }
    }
}

// ---------------------------------------------------------------------------
extern "C" void kernel_launch(void* const* d_in, const int* in_sizes, int n_in,
                              void* d_out, int out_size, void* d_ws, size_t ws_size,
                              hipStream_t stream)
{
    const float* x        = (const float*)d_in[0];
    const float* ln_gamma = (const float*)d_in[1];
    const float* ln_beta  = (const float*)d_in[2];
    const float* P        = (const float*)d_in[3];
    const float* dlt      = (const float*)d_in[4];
    const float* phi_w    = (const float*)d_in[5];
    const float* phi_bias = (const float*)d_in[6];
    const float* toep     = (const float*)d_in[7];
    const float* Wq       = (const float*)d_in[8];
    const float* bq       = (const float*)d_in[9];
    const float* g_logit  = (const float*)d_in[10];
    const int*   step     = (const int*)d_in[11];
    float* out = (float*)d_out;

    char* w = (char*)d_ws;
    unsigned short* xn  = (unsigned short*)(w);                    // 67,108,864 B
    unsigned short* u   = (unsigned short*)(w + 67108864);         //  8,388,608 B
    unsigned short* PT  = (unsigned short*)(w + 75497472);         //  1,048,576 B
    unsigned short* WT  = (unsigned short*)(w + 76546048);         //  1,048,576 B
    float*          W2T = (float*)(w + 77594624);                  //    262,144 B
    float*          feat= (float*)(w + 77856768);                  //     65,536 B
    float*          gs  = (float*)(w + 77922304);                  //      8,192 B
    float*          bgs = (float*)(w + 77930496);                  //      8,192 B

    ln_kernel<<<dim3(B_ * L_), dim3(256), 0, stream>>>(x, ln_gamma, ln_beta, xn, feat);
    pt_kernel<<<dim3(D_), dim3(256), 0, stream>>>(P, PT);
    w2_kernel<<<dim3(R_), dim3(256), 0, stream>>>(dlt, toep, W2T);
    wt_kernel<<<dim3(D_), dim3(256), 0, stream>>>(W2T, Wq, WT);
    scale_kernel<<<dim3(L_), dim3(256), 0, stream>>>(phi_bias, phi_w, feat, bq,
                                                     g_logit, step, gs, bgs);
    gemm1_kernel<<<dim3(256, 2), dim3(256), 0, stream>>>(xn, PT, u);
    gemm2_kernel<<<dim3(128, 16), dim3(256), 0, stream>>>(u, WT, gs, bgs, out);
}

// Round 2
// 397.190 us; speedup vs baseline: 1.0606x; 1.0606x over previous
//
#include <hip/hip_runtime.h>
#include <cstdint>
#include <math.h>

#define B_ 8
#define L_ 2048
#define D_ 2048
#define R_ 256

typedef __bf16 bf16x8 __attribute__((ext_vector_type(8)));
typedef float f32x4 __attribute__((ext_vector_type(4)));

__device__ __forceinline__ unsigned short f2bf(float f) {
    uint32_t u = __builtin_bit_cast(uint32_t, f);
    u += 0x7FFFu + ((u >> 16) & 1u);
    return (unsigned short)(u >> 16);
}

#define GLDS16(gp, lp)                                                          \
    __builtin_amdgcn_global_load_lds(                                           \
        (const __attribute__((address_space(1))) void*)(gp),                    \
        (__attribute__((address_space(3))) void*)(lp), 16, 0, 0)

// ---------------------------------------------------------------------------
// Kernel 1: LayerNorm (fp32 -> bf16) + feat via closed form, ONE reduction:
// feat = mean(n) = (rstd*(Sxg - mean*Sg) + Sb) / D
// ---------------------------------------------------------------------------
__global__ __launch_bounds__(256) void ln_kernel(
    const float* __restrict__ x, const float* __restrict__ gamma,
    const float* __restrict__ beta, unsigned short* __restrict__ xn,
    float* __restrict__ feat)
{
    const int row  = blockIdx.x;
    const int t    = threadIdx.x;
    const int w    = t >> 6, lane = t & 63;
    const float4* x4 = (const float4*)(x + (size_t)row * D_);
    const float4* g4 = (const float4*)gamma;
    const float4* b4 = (const float4*)beta;
    float4 a  = x4[t];
    float4 b  = x4[t + 256];
    float4 g0 = g4[t], g1 = g4[t + 256];
    float4 e0 = b4[t], e1 = b4[t + 256];

    float s   = a.x + a.y + a.z + a.w + b.x + b.y + b.z + b.w;
    float sq  = a.x*a.x + a.y*a.y + a.z*a.z + a.w*a.w
              + b.x*b.x + b.y*b.y + b.z*b.z + b.w*b.w;
    float sxg = a.x*g0.x + a.y*g0.y + a.z*g0.z + a.w*g0.w
              + b.x*g1.x + b.y*g1.y + b.z*g1.z + b.w*g1.w;
    float sg  = g0.x + g0.y + g0.z + g0.w + g1.x + g1.y + g1.z + g1.w;
    float sb  = e0.x + e0.y + e0.z + e0.w + e1.x + e1.y + e1.z + e1.w;

    __shared__ float red[20];
#pragma unroll
    for (int o = 32; o; o >>= 1) {
        s   += __shfl_down(s, o);
        sq  += __shfl_down(sq, o);
        sxg += __shfl_down(sxg, o);
        sg  += __shfl_down(sg, o);
        sb  += __shfl_down(sb, o);
    }
    if (lane == 0) {
        red[w] = s; red[4+w] = sq; red[8+w] = sxg; red[12+w] = sg; red[16+w] = sb;
    }
    __syncthreads();
    float S    = red[0] + red[1] + red[2] + red[3];
    float SQ   = red[4] + red[5] + red[6] + red[7];
    float SXG  = red[8] + red[9] + red[10] + red[11];
    float SG   = red[12] + red[13] + red[14] + red[15];
    float SB   = red[16] + red[17] + red[18] + red[19];
    float mean = S * (1.0f / D_);
    float var  = SQ * (1.0f / D_) - mean * mean;
    float rstd = rsqrtf(var + 1e-5f);
    if (t == 0)
        feat[row] = (rstd * (SXG - mean * SG) + SB) * (1.0f / D_);

    float n[8];
    n[0] = (a.x - mean) * rstd * g0.x + e0.x;
    n[1] = (a.y - mean) * rstd * g0.y + e0.y;
    n[2] = (a.z - mean) * rstd * g0.z + e0.z;
    n[3] = (a.w - mean) * rstd * g0.w + e0.w;
    n[4] = (b.x - mean) * rstd * g1.x + e1.x;
    n[5] = (b.y - mean) * rstd * g1.y + e1.y;
    n[6] = (b.z - mean) * rstd * g1.z + e1.z;
    n[7] = (b.w - mean) * rstd * g1.w + e1.w;

    ushort4 o0, o1;
    o0.x = f2bf(n[0]); o0.y = f2bf(n[1]); o0.z = f2bf(n[2]); o0.w = f2bf(n[3]);
    o1.x = f2bf(n[4]); o1.y = f2bf(n[5]); o1.z = f2bf(n[6]); o1.w = f2bf(n[7]);
    ((ushort4*)(xn + (size_t)row * D_))[t]       = o0;
    ((ushort4*)(xn + (size_t)row * D_))[t + 256] = o1;
}

// ---------------------------------------------------------------------------
// Kernel 2: P (D x R fp32) -> PT (R x D bf16), LDS tile transpose, 16B stores
// ---------------------------------------------------------------------------
__global__ __launch_bounds__(256) void pt_kernel(
    const float* __restrict__ P, unsigned short* __restrict__ PT)
{
    __shared__ unsigned short sT[64 * 256];
    const int k0 = blockIdx.x * 64, t = threadIdx.x;
#pragma unroll 8
    for (int j = 0; j < 64; j++)
        sT[j * 256 + t] = f2bf(P[(size_t)(k0 + j) * R_ + t]);
    __syncthreads();
#pragma unroll
    for (int c = 0; c < 16; c++) {
        ushort4 v;
        v.x = sT[(c * 4 + 0) * 256 + t];
        v.y = sT[(c * 4 + 1) * 256 + t];
        v.z = sT[(c * 4 + 2) * 256 + t];
        v.w = sT[(c * 4 + 3) * 256 + t];
        *(ushort4*)(PT + (size_t)t * D_ + k0 + c * 4) = v;
    }
}

// ---------------------------------------------------------------------------
// Kernel 3: W2T[s][q] = sum_r dlt_T[r][q] * toep[r - s + 127]
// ---------------------------------------------------------------------------
__global__ __launch_bounds__(256) void w2_kernel(
    const float* __restrict__ dlt, const float* __restrict__ toep,
    float* __restrict__ W2T)
{
    int s = blockIdx.x, q = threadIdx.x;
    int r0 = s - 127; if (r0 < 0) r0 = 0;
    int r1 = s + 127; if (r1 > 255) r1 = 255;
    float acc = 0.f;
    for (int r = r0; r <= r1; r++)
        acc += dlt[(size_t)r * R_ + q] * toep[r - s + 127];
    W2T[(size_t)s * R_ + q] = acc;
}

// ---------------------------------------------------------------------------
// Kernel 4: WT[d][q] = sum_s W2T[s][q] * Wq[s][d], 4 d per thread
// ---------------------------------------------------------------------------
__global__ __launch_bounds__(256) void wt_kernel(
    const float* __restrict__ W2T, const float* __restrict__ Wq,
    unsigned short* __restrict__ WT)
{
    const int d0 = blockIdx.x * 4, q = threadIdx.x;
    float a0 = 0.f, a1 = 0.f, a2 = 0.f, a3 = 0.f;
    for (int s = 0; s < R_; s++) {
        float w2 = W2T[(size_t)s * R_ + q];
        const float* wr = Wq + (size_t)s * D_ + d0;
        a0 += w2 * wr[0]; a1 += w2 * wr[1]; a2 += w2 * wr[2]; a3 += w2 * wr[3];
    }
    WT[(size_t)(d0 + 0) * R_ + q] = f2bf(a0);
    WT[(size_t)(d0 + 1) * R_ + q] = f2bf(a1);
    WT[(size_t)(d0 + 2) * R_ + q] = f2bf(a2);
    WT[(size_t)(d0 + 3) * R_ + q] = f2bf(a3);
}

// ---------------------------------------------------------------------------
// Kernel 5: gs[l] = g(l)*scale[l], bgs[l] = bq[l]*gs[l]
// ---------------------------------------------------------------------------
__global__ __launch_bounds__(256) void scale_kernel(
    const float* __restrict__ phi_bias, const float* __restrict__ phi_w,
    const float* __restrict__ feat, const float* __restrict__ bq,
    const float* __restrict__ g_logit, const int* __restrict__ step,
    float* __restrict__ gs, float* __restrict__ bgs)
{
    int l = blockIdx.x, k = threadIdx.x;
    int w = k >> 6, lane = k & 63;
    float arg = 3.14159265358979323846f * ((float)l + 0.5f) * (float)k * (1.0f / L_);
    float cv = cosf(arg);
    float pb = phi_bias[(size_t)l * R_ + k];
    float pw = phi_w[k];
    __shared__ float red[12];
#pragma unroll
    for (int o = 32; o; o >>= 1) {
        cv += __shfl_down(cv, o);
        pb += __shfl_down(pb, o);
        pw += __shfl_down(pw, o);
    }
    if (lane == 0) { red[w] = cv; red[4 + w] = pb; red[8 + w] = pw; }
    __syncthreads();
    if (k == 0) {
        float cs  = red[0] + red[1] + red[2] + red[3];
        float pbs = red[4] + red[5] + red[6] + red[7];
        float pws = red[8] + red[9] + red[10] + red[11];
        float fb = 0.f;
        for (int b = 0; b < B_; b++) fb += feat[(size_t)b * L_ + l];
        fb *= (1.0f / B_);
        float det = fminf((float)step[0] / 2000.0f, 1.0f);
        float sc  = (det * cs + pbs + fb * pws) * (1.0f / R_);
        float gl  = g_logit[l >> 10];
        float gg  = 1.0f / (1.0f + expf(-gl));
        gs[l]  = gg * sc;
        bgs[l] = bq[l] * gg * sc;
    }
}

// ---------------------------------------------------------------------------
// GEMM1: u(16384x256 bf16) = xn @ P   (B supplied transposed: PT, R x D)
// BM=64, BN=128, BK=64 (two ld=32 half-tiles); grid x=n (2), y=m (256)
// ---------------------------------------------------------------------------
__global__ __launch_bounds__(256, 2) void gemm1_kernel(
    const unsigned short* __restrict__ A,   // xn, lda=2048
    const unsigned short* __restrict__ BT,  // PT,  ldb=2048
    unsigned short* __restrict__ U)         // 16384x256
{
    __shared__ __align__(16) unsigned short sA[2][64 * 32];
    __shared__ __align__(16) unsigned short sB[2][128 * 32];
    const int tid  = threadIdx.x;
    const int n0   = blockIdx.x * 128;
    const int m0   = blockIdx.y * 64;
    const int w    = tid >> 6, lane = tid & 63;
    const int quad = lane >> 4, m16 = lane & 15;
    const int wm   = (w >> 1) * 32, wn = (w & 1) * 64;
    const int ra   = tid >> 2, sa = tid & 3;

    f32x4 acc[2][4] = {};

    for (int kc = 0; kc < 2048; kc += 64) {
        const unsigned short* ap = A + (size_t)(m0 + ra) * 2048 + kc + sa * 8;
        GLDS16(ap,      sA[0] + tid * 8);
        GLDS16(ap + 32, sA[1] + tid * 8);
#pragma unroll
        for (int i = 0; i < 2; i++) {
            int idx = i * 256 + tid;
            int r = idx >> 2, seg = idx & 3;
            const unsigned short* bp = BT + (size_t)(n0 + r) * 2048 + kc + seg * 8;
            GLDS16(bp,      sB[0] + idx * 8);
            GLDS16(bp + 32, sB[1] + idx * 8);
        }
        __syncthreads();
#pragma unroll
        for (int h = 0; h < 2; h++) {
            bf16x8 af[2], bf[4];
#pragma unroll
            for (int i = 0; i < 2; i++)
                af[i] = *(const bf16x8*)(sA[h] + ((wm + i * 16 + m16) * 32 + quad * 8));
#pragma unroll
            for (int j = 0; j < 4; j++)
                bf[j] = *(const bf16x8*)(sB[h] + ((wn + j * 16 + m16) * 32 + quad * 8));
#pragma unroll
            for (int i = 0; i < 2; i++)
#pragma unroll
                for (int j = 0; j < 4; j++)
                    acc[i][j] = __builtin_amdgcn_mfma_f32_16x16x32_bf16(
                        af[i], bf[j], acc[i][j], 0, 0, 0);
        }
        __syncthreads();
    }

#pragma unroll
    for (int i = 0; i < 2; i++)
#pragma unroll
        for (int j = 0; j < 4; j++) {
            int col = n0 + wn + j * 16 + m16;
#pragma unroll
            for (int r = 0; r < 4; r++) {
                int row = m0 + wm + i * 16 + quad * 4 + r;
                U[(size_t)row * 256 + col] = f2bf(acc[i][j][r]);
            }
        }
}

// ---------------------------------------------------------------------------
// GEMM2: out(16384x2048 f32) = u @ W_eff (via WT), epilogue *gs[col]+bgs[col]
// BM=128, BN=128, BK=64 (two ld=32 half-tiles); grid x=n (16), y=m (128)
// ---------------------------------------------------------------------------
__global__ __launch_bounds__(256, 3) void gemm2_kernel(
    const unsigned short* __restrict__ A,   // u,  lda=256
    const unsigned short* __restrict__ BT,  // WT, ldb=256
    const float* __restrict__ gs, const float* __restrict__ bgs,
    float* __restrict__ out)
{
    __shared__ __align__(16) unsigned short sA[2][128 * 32];
    __shared__ __align__(16) unsigned short sB[2][128 * 32];
    const int tid  = threadIdx.x;
    const int n0   = blockIdx.x * 128;
    const int m0   = blockIdx.y * 128;
    const int w    = tid >> 6, lane = tid & 63;
    const int quad = lane >> 4, m16 = lane & 15;
    const int wm   = (w >> 1) * 64, wn = (w & 1) * 64;

    float gv[4], bv[4];
#pragma unroll
    for (int j = 0; j < 4; j++) {
        int col = n0 + wn + j * 16 + m16;
        gv[j] = gs[col];
        bv[j] = bgs[col];
    }

    f32x4 acc[4][4] = {};

    for (int kc = 0; kc < 256; kc += 64) {
#pragma unroll
        for (int i = 0; i < 2; i++) {
            int idx = i * 256 + tid;
            int r = idx >> 2, seg = idx & 3;
            const unsigned short* ap = A + (size_t)(m0 + r) * 256 + kc + seg * 8;
            const unsigned short* bp = BT + (size_t)(n0 + r) * 256 + kc + seg * 8;
            GLDS16(ap,      sA[0] + idx * 8);
            GLDS16(ap + 32, sA[1] + idx * 8);
            GLDS16(bp,      sB[0] + idx * 8);
            GLDS16(bp + 32, sB[1] + idx * 8);
        }
        __syncthreads();
#pragma unroll
        for (int h = 0; h < 2; h++) {
            bf16x8 af[4], bf[4];
#pragma unroll
            for (int i = 0; i < 4; i++)
                af[i] = *(const bf16x8*)(sA[h] + ((wm + i * 16 + m16) * 32 + quad * 8));
#pragma unroll
            for (int j = 0; j < 4; j++)
                bf[j] = *(const bf16x8*)(sB[h] + ((wn + j * 16 + m16) * 32 + quad * 8));
#pragma unroll
            for (int i = 0; i < 4; i++)
#pragma unroll
                for (int j = 0; j < 4; j++)
                    acc[i][j] = __builtin_amdgcn_mfma_f32_16x16x32_bf16(
                        af[i], bf[j], acc[i][j], 0, 0, 0);
        }
        __syncthreads();
    }

    // row-major streaming epilogue: per (i,r) row, 4x16 lanes cover 64 cols
#pragma unroll
    for (int i = 0; i < 4; i++)
#pragma unroll
        for (int r = 0; r < 4; r++) {
            int row = m0 + wm + i * 16 + quad * 4 + r;
            float* op = out + (size_t)row * 2048 + n0 + wn;
#pragma unroll
            for (int j = 0; j < 4; j++)
                op[j * 16 + m16] = acc[i][j][r] * gv[j] + bv[j];
        }
}

// ---------------------------------------------------------------------------
extern "C" void kernel_launch(void* const* d_in, const int* in_sizes, int n_in,
                              void* d_out, int out_size, void* d_ws, size_t ws_size,
                              hipStream_t stream)
{
    const float* x        = (const float*)d_in[0];
    const float* ln_gamma = (const float*)d_in[1];
    const float* ln_beta  = (const float*)d_in[2];
    const float* P        = (const float*)d_in[3];
    const float* dlt      = (const float*)d_in[4];
    const float* phi_w    = (const float*)d_in[5];
    const float* phi_bias = (const float*)d_in[6];
    const float* toep     = (const float*)d_in[7];
    const float* Wq       = (const float*)d_in[8];
    const float* bq       = (const float*)d_in[9];
    const float* g_logit  = (const float*)d_in[10];
    const int*   step     = (const int*)d_in[11];
    float* out = (float*)d_out;

    char* w = (char*)d_ws;
    unsigned short* xn  = (unsigned short*)(w);                    // 67,108,864 B
    unsigned short* u   = (unsigned short*)(w + 67108864);         //  8,388,608 B
    unsigned short* PT  = (unsigned short*)(w + 75497472);         //  1,048,576 B
    unsigned short* WT  = (unsigned short*)(w + 76546048);         //  1,048,576 B
    float*          W2T = (float*)(w + 77594624);                  //    262,144 B
    float*          feat= (float*)(w + 77856768);                  //     65,536 B
    float*          gs  = (float*)(w + 77922304);                  //      8,192 B
    float*          bgs = (float*)(w + 77930496);                  //      8,192 B

    ln_kernel<<<dim3(B_ * L_), dim3(256), 0, stream>>>(x, ln_gamma, ln_beta, xn, feat);
    pt_kernel<<<dim3(32), dim3(256), 0, stream>>>(P, PT);
    w2_kernel<<<dim3(R_), dim3(256), 0, stream>>>(dlt, toep, W2T);
    wt_kernel<<<dim3(512), dim3(256), 0, stream>>>(W2T, Wq, WT);
    scale_kernel<<<dim3(L_), dim3(256), 0, stream>>>(phi_bias, phi_w, feat, bq,
                                                     g_logit, step, gs, bgs);
    gemm1_kernel<<<dim3(2, 256), dim3(256), 0, stream>>>(xn, PT, u);
    gemm2_kernel<<<dim3(16, 128), dim3(256), 0, stream>>>(u, WT, gs, bgs, out);
}